// Round 2
// baseline (189.670 us; speedup 1.0000x reference)
//
#include <hip/hip_runtime.h>

#define T_DATA 20000
#define S_NO   128
#define T_HIST 100
#define NELEM  (T_DATA * S_NO)   // 2,560,000

__device__ __forceinline__ float sigm(float v) {
    return 1.0f / (1.0f + __expf(-v));
}

// ---------------------------------------------------------------------------
// K1: prep (17 blocks).
//  blocks 0..15: transpose C (each handles 1024 elements, coalesced reads)
//  block 16:     build ancestor kernel (transposed [j][s]) + history kernel
//                ([s][j]) + flag = any(K_hist != 0)
// ---------------------------------------------------------------------------
__global__ void __launch_bounds__(256) k1_prep(const float* __restrict__ C,
                        const float* __restrict__ K_spike,
                        const float* __restrict__ tau_spike,
                        const float* __restrict__ delta_spike,
                        const float* __restrict__ tau_hist,
                        const float* __restrict__ K_hist,
                        const float* __restrict__ delta_hist,
                        float* __restrict__ Ct,
                        float* __restrict__ anc_kT,
                        float* __restrict__ hist_k,
                        int* __restrict__ flag) {
    const int tid = threadIdx.x;
    const int b   = blockIdx.x;
    if (b < 16) {
        // transpose slab: elements q in [b*1024, b*1024+1024)
#pragma unroll
        for (int i = 0; i < 4; ++i) {
            const int q = b * 1024 + i * 256 + tid;   // q = s*128 + k
            Ct[(q & 127) * S_NO + (q >> 7)] = C[q];
        }
        return;
    }
    // block 16: kernel tables + flag
    const int s    = tid & 127;
    const int half = tid >> 7;            // 0 or 1 -> j chunks of 50
    {   // ancestor (spike) kernel, stored transposed: anc_kT[j*128 + s]
        float d  = delta_spike[s];
        float i0 = __expf(-tau_spike[0]);
        float i1 = __expf(-tau_spike[1]);
        float i2 = __expf(-tau_spike[2]);
        float k0 = K_spike[s * 3 + 0], k1 = K_spike[s * 3 + 1], k2 = K_spike[s * 3 + 2];
        for (int j = half * 50; j < half * 50 + 50; ++j) {
            float t  = fmaxf((float)j - d, 0.0f);
            float x0 = t * i0, x1 = t * i1, x2 = t * i2;
            anc_kT[j * S_NO + s] =
                k0 * x0 * __expf(-x0) + k1 * x1 * __expf(-x1) + k2 * x2 * __expf(-x2);
        }
    }
    {   // history kernel, per-subunit row-major: hist_k[s*100 + j]
        float d  = delta_hist[s];
        float i0 = __expf(-tau_hist[0]);
        float i1 = __expf(-tau_hist[1]);
        float i2 = __expf(-tau_hist[2]);
        float k0 = K_hist[s * 3 + 0], k1 = K_hist[s * 3 + 1], k2 = K_hist[s * 3 + 2];
        for (int j = half * 50; j < half * 50 + 50; ++j) {
            float t  = fmaxf((float)j - d, 0.0f);
            float x0 = t * i0, x1 = t * i1, x2 = t * i2;
            hist_k[s * T_HIST + j] =
                k0 * x0 * __expf(-x0) + k1 * x1 * __expf(-x1) + k2 * x2 * __expf(-x2);
        }
    }
    if (tid == 0) *flag = 0;
    __syncthreads();
    if (tid < 128) {
        if (K_hist[s * 3] != 0.0f || K_hist[s * 3 + 1] != 0.0f || K_hist[s * 3 + 2] != 0.0f)
            atomicOr(flag, 1);
    }
}

// ---------------------------------------------------------------------------
// K2: dual GEMM  A = Z @ C^T (-> ws), R = Y @ C^T (-> out1)
// 16 timesteps per block, 256 threads: thread (s, th) computes 8 t-rows.
// ---------------------------------------------------------------------------
__global__ void __launch_bounds__(256) k2_gemm(const float* __restrict__ Z,
                                               const float* __restrict__ Y,
                                               const float* __restrict__ Ct,
                                               float* __restrict__ A,
                                               float* __restrict__ R) {
    __shared__ float Zt[16][128];
    __shared__ float Yt[16][128];
    const int t0  = blockIdx.x * 16;
    const int tid = threadIdx.x;
    {
        const float4* Zg = (const float4*)(Z + t0 * S_NO);
        const float4* Yg = (const float4*)(Y + t0 * S_NO);
        float4* Zl = (float4*)&Zt[0][0];
        float4* Yl = (float4*)&Yt[0][0];
        for (int q = tid; q < 512; q += 256) { Zl[q] = Zg[q]; Yl[q] = Yg[q]; }
    }
    __syncthreads();
    const int s  = tid & 127;
    const int tb = (tid >> 7) * 8;
    float accA[8] = {0, 0, 0, 0, 0, 0, 0, 0};
    float accR[8] = {0, 0, 0, 0, 0, 0, 0, 0};
    for (int k4 = 0; k4 < 32; ++k4) {
        const float c0 = Ct[(k4 * 4 + 0) * S_NO + s];
        const float c1 = Ct[(k4 * 4 + 1) * S_NO + s];
        const float c2 = Ct[(k4 * 4 + 2) * S_NO + s];
        const float c3 = Ct[(k4 * 4 + 3) * S_NO + s];
#pragma unroll
        for (int i = 0; i < 8; ++i) {
            float4 z = *(const float4*)&Zt[tb + i][k4 * 4];
            accA[i] = fmaf(c0, z.x, fmaf(c1, z.y, fmaf(c2, z.z, fmaf(c3, z.w, accA[i]))));
            float4 y = *(const float4*)&Yt[tb + i][k4 * 4];
            accR[i] = fmaf(c0, y.x, fmaf(c1, y.y, fmaf(c2, y.z, fmaf(c3, y.w, accR[i]))));
        }
    }
#pragma unroll
    for (int i = 0; i < 8; ++i) {
        A[(t0 + tb + i) * S_NO + s] = accA[i];
        R[(t0 + tb + i) * S_NO + s] = accR[i];
    }
}

// ---------------------------------------------------------------------------
// K3: fused 100-tap causal conv + final nonlinear map (fast path).
//   F[t,s] = sum_{j=0..99} A[t-1-j, s] * anc_k[s][j]   (A index <0 -> 0)
// Block: 40 timesteps x 64 subunits; 10-deep register rolling window,
// unroll capped at 10 (index pattern has period 10 -> stays static).
// flag==0: apply sigmoid map, write all 4 outputs (F never hits HBM).
// flag!=0: write F to ws; k4_scan finishes exactly.
// ---------------------------------------------------------------------------
__global__ void __launch_bounds__(256) k3_fused(const float* __restrict__ A,
                                                const float* __restrict__ anc_kT,
                                                const float* __restrict__ S_conv,
                                                const float* __restrict__ noise,
                                                const float* __restrict__ W_sub,
                                                const float* __restrict__ theta_syn,
                                                const float* __restrict__ theta_spike,
                                                const float* __restrict__ W_spike,
                                                const int* __restrict__ flag,
                                                float* __restrict__ out0,
                                                float* __restrict__ out1,
                                                float* __restrict__ out2,
                                                float* __restrict__ out3,
                                                float* __restrict__ Fws) {
    __shared__ float Al[141 * 64];        // row 0 = dummy (lets j=99 prefetch run unguarded)
    const int tstart = blockIdx.x * 40;
    const int shalf  = blockIdx.y;
    const int tid    = threadIdx.x;
    // stage A rows u = tstart-100 .. tstart+39 into Al rows 1..140 (0 if u<0)
    for (int q = tid; q < 140 * 16; q += 256) {
        const int row = q >> 4, c4 = q & 15;
        const int u  = tstart - 100 + row;
        float4 v = make_float4(0.f, 0.f, 0.f, 0.f);
        if (u >= 0) v = *(const float4*)&A[u * S_NO + shalf * 64 + c4 * 4];
        *(float4*)&Al[(row + 1) * 64 + c4 * 4] = v;
    }
    __syncthreads();
    const int sl    = tid & 63;
    const int tg    = tid >> 6;           // 0..3, 10 timesteps each
    const int sg    = shalf * 64 + sl;
    const int rbase = tg * 10;
    float acc[10] = {0, 0, 0, 0, 0, 0, 0, 0, 0, 0};
    float W[10];
#pragma unroll
    for (int i = 0; i < 10; ++i) W[i] = Al[(rbase + 100 + i) * 64 + sl];
#pragma unroll 10
    for (int j = 0; j < 100; ++j) {
        const float kv = anc_kT[j * S_NO + sg];
#pragma unroll
        for (int i = 0; i < 10; ++i)
            acc[i] = fmaf(W[(((i - j) % 10) + 10) % 10], kv, acc[i]);
        // prefetch row for next j; at j=99 reads dummy-adjacent valid row, unused
        W[(10 - ((j + 1) % 10)) % 10] = Al[(rbase + 99 - j) * 64 + sl];
    }
    const int T0 = tstart + rbase;
    if (*flag == 0) {
        const float tsy = theta_syn[sg], wsub = W_sub[sg];
        const float wsp = W_spike[sg],  tsp  = theta_spike[sg];
#pragma unroll
        for (int i = 0; i < 10; ++i) {
            const int n = (T0 + i) * S_NO + sg;
            const float basev = S_conv[n] + tsy + out1[n] + acc[i];
            const float x  = sigm(basev);
            const float dn = fmaf(x, wsp, tsp);
            const float z  = sigm(dn + noise[n]);
            out0[n] = x * wsub;
            out1[n] = z;
            out2[n] = dn;
            out3[n] = dn;
        }
    } else {
#pragma unroll
        for (int i = 0; i < 10; ++i) Fws[(T0 + i) * S_NO + sg] = acc[i];
    }
}

// ---------------------------------------------------------------------------
// K4: exact sequential recurrence (only when hist kernel != 0).
// One wave per subunit; LDS ring of Z history + wave shuffle reduction.
// ---------------------------------------------------------------------------
__global__ void __launch_bounds__(64) k4_scan(const float* __restrict__ S_conv,
                                              const float* __restrict__ noise,
                                              const float* __restrict__ W_sub,
                                              const float* __restrict__ theta_syn,
                                              const float* __restrict__ theta_spike,
                                              const float* __restrict__ W_spike,
                                              const float* __restrict__ hist_k,
                                              const int* __restrict__ flag,
                                              const float* __restrict__ Fws,
                                              float* __restrict__ out0,
                                              float* __restrict__ out1,
                                              float* __restrict__ out2,
                                              float* __restrict__ out3) {
    if (*flag == 0) return;
    __shared__ float zr[128];
    const int s = blockIdx.x;
    const int l = threadIdx.x;
    zr[l] = 0.0f; zr[l + 64] = 0.0f;      // single wave: no barrier needed
    const float hk0 = (l < T_HIST) ? hist_k[s * T_HIST + l] : 0.0f;
    const float hk1 = (l + 64 < T_HIST) ? hist_k[s * T_HIST + l + 64] : 0.0f;
    const float tsy = theta_syn[s], wsub = W_sub[s];
    const float wsp = W_spike[s],  tsp  = theta_spike[s];
    for (int t = 0; t < T_DATA; ++t) {
        float fh = hk0 * zr[(t - 1 - l) & 127];
        fh = fmaf(hk1, zr[(t - 65 - l) & 127], fh);
#pragma unroll
        for (int m = 1; m < 64; m <<= 1) fh += __shfl_xor(fh, m, 64);
        const int n = t * S_NO + s;
        const float basev = S_conv[n] + tsy + out1[n] + Fws[n];
        const float x  = sigm(basev + fh);
        const float dn = fmaf(x, wsp, tsp);
        const float z  = sigm(dn + noise[n]);
        if (l == 0) {
            out0[n] = x * wsub;
            out1[n] = z;
            out2[n] = dn;
            out3[n] = dn;
            zr[t & 127] = z;
        }
    }
}

// ---------------------------------------------------------------------------
extern "C" void kernel_launch(void* const* d_in, const int* in_sizes, int n_in,
                              void* d_out, int out_size, void* d_ws, size_t ws_size,
                              hipStream_t stream) {
    const float* S_conv  = (const float*)d_in[0];
    const float* Y_anc   = (const float*)d_in[1];
    const float* Z_anc   = (const float*)d_in[2];
    const float* noise   = (const float*)d_in[3];
    const float* C_den   = (const float*)d_in[4];
    const float* W_sub   = (const float*)d_in[5];
    const float* th_syn  = (const float*)d_in[6];
    const float* K_spk   = (const float*)d_in[7];
    const float* tau_spk = (const float*)d_in[8];
    const float* dl_spk  = (const float*)d_in[9];
    const float* th_spk  = (const float*)d_in[10];
    const float* W_spk   = (const float*)d_in[11];
    const float* tau_h   = (const float*)d_in[12];
    const float* K_h     = (const float*)d_in[13];
    const float* dl_h    = (const float*)d_in[14];

    float* out  = (float*)d_out;
    float* out0 = out;
    float* out1 = out + NELEM;
    float* out2 = out + 2 * NELEM;
    float* out3 = out + 3 * NELEM;

    // workspace: A (2.56M) | F (2.56M) | Ct (16384) | anc_kT | hist_k | flag
    float* ws     = (float*)d_ws;
    float* wsA    = ws;
    float* wsF    = ws + NELEM;
    float* Ct     = ws + 2 * NELEM;
    float* anc_kT = Ct + 16384;
    float* hist_k = anc_kT + T_HIST * S_NO;
    int*   flag   = (int*)(hist_k + S_NO * T_HIST);

    k1_prep<<<17, 256, 0, stream>>>(C_den, K_spk, tau_spk, dl_spk, tau_h, K_h, dl_h,
                                    Ct, anc_kT, hist_k, flag);
    // A -> ws, R -> out1
    k2_gemm<<<T_DATA / 16, 256, 0, stream>>>(Z_anc, Y_anc, Ct, wsA, out1);
    // fused conv + final (reads A from ws, R from out1)
    k3_fused<<<dim3(T_DATA / 40, 2), 256, 0, stream>>>(wsA, anc_kT, S_conv, noise,
                                                       W_sub, th_syn, th_spk, W_spk,
                                                       flag, out0, out1, out2, out3, wsF);
    // exact sequential path (no-op when hist kernel is all-zero)
    k4_scan<<<S_NO, 64, 0, stream>>>(S_conv, noise, W_sub, th_syn, th_spk, W_spk,
                                     hist_k, flag, wsF, out0, out1, out2, out3);
}

// Round 3
// 168.982 us; speedup vs baseline: 1.1224x; 1.1224x over previous
//
#include <hip/hip_runtime.h>

#define T_DATA 20000
#define S_NO   128
#define T_HIST 100
#define J_PAD  112              // conv taps padded to 7 chunks of 16 (zeros past 99)
#define NELEM  (T_DATA * S_NO)  // 2,560,000

__device__ __forceinline__ float sigm(float v) {
    return 1.0f / (1.0f + __expf(-v));
}

__device__ __forceinline__ void fma4(float4& a, float s, const float4 c) {
    a.x = fmaf(s, c.x, a.x); a.y = fmaf(s, c.y, a.y);
    a.z = fmaf(s, c.z, a.z); a.w = fmaf(s, c.w, a.w);
}

// ---------------------------------------------------------------------------
// K1: prep (17 blocks).
//  blocks 0..15: transpose C -> Ct[k][s]
//  block 16:     ancestor kernel transposed [j][s], j zero-padded to 112;
//                history kernel [s][j]; flag = any(K_hist != 0)
// ---------------------------------------------------------------------------
__global__ void __launch_bounds__(256) k1_prep(const float* __restrict__ C,
                        const float* __restrict__ K_spike,
                        const float* __restrict__ tau_spike,
                        const float* __restrict__ delta_spike,
                        const float* __restrict__ tau_hist,
                        const float* __restrict__ K_hist,
                        const float* __restrict__ delta_hist,
                        float* __restrict__ Ct,
                        float* __restrict__ anc_kT,
                        float* __restrict__ hist_k,
                        int* __restrict__ flag) {
    const int tid = threadIdx.x;
    const int b   = blockIdx.x;
    if (b < 16) {
#pragma unroll
        for (int i = 0; i < 4; ++i) {
            const int q = b * 1024 + i * 256 + tid;   // q = s*128 + k
            Ct[(q & 127) * S_NO + (q >> 7)] = C[q];
        }
        return;
    }
    const int s    = tid & 127;
    const int half = tid >> 7;            // 0/1 -> j chunks of 56
    {   // ancestor kernel transposed, padded: anc_kT[j*128 + s], j in [0,112)
        float d  = delta_spike[s];
        float i0 = __expf(-tau_spike[0]);
        float i1 = __expf(-tau_spike[1]);
        float i2 = __expf(-tau_spike[2]);
        float k0 = K_spike[s * 3 + 0], k1 = K_spike[s * 3 + 1], k2 = K_spike[s * 3 + 2];
        for (int j = half * 56; j < half * 56 + 56; ++j) {
            float v = 0.0f;
            if (j < T_HIST) {
                float t  = fmaxf((float)j - d, 0.0f);
                float x0 = t * i0, x1 = t * i1, x2 = t * i2;
                v = k0 * x0 * __expf(-x0) + k1 * x1 * __expf(-x1) + k2 * x2 * __expf(-x2);
            }
            anc_kT[j * S_NO + s] = v;
        }
    }
    {   // history kernel per-subunit: hist_k[s*100 + j]
        float d  = delta_hist[s];
        float i0 = __expf(-tau_hist[0]);
        float i1 = __expf(-tau_hist[1]);
        float i2 = __expf(-tau_hist[2]);
        float k0 = K_hist[s * 3 + 0], k1 = K_hist[s * 3 + 1], k2 = K_hist[s * 3 + 2];
        for (int j = half * 50; j < half * 50 + 50; ++j) {
            float t  = fmaxf((float)j - d, 0.0f);
            float x0 = t * i0, x1 = t * i1, x2 = t * i2;
            hist_k[s * T_HIST + j] =
                k0 * x0 * __expf(-x0) + k1 * x1 * __expf(-x1) + k2 * x2 * __expf(-x2);
        }
    }
    if (tid == 0) *flag = 0;
    __syncthreads();
    if (tid < 128) {
        if (K_hist[s * 3] != 0.0f || K_hist[s * 3 + 1] != 0.0f || K_hist[s * 3 + 2] != 0.0f)
            atomicOr(flag, 1);
    }
}

// ---------------------------------------------------------------------------
// K2: dual GEMM  A = Z @ C^T (-> ws), R = Y @ C^T (-> out1)
// Block: 32 t-rows x 128 s. Thread: 4t x 4s register tile for BOTH outputs.
// Per k4-step: 8 broadcast ds_read_b128 serve 128 FMAs (VALU-bound, not LDS).
// ---------------------------------------------------------------------------
__global__ void __launch_bounds__(256) k2_gemm(const float* __restrict__ Z,
                                               const float* __restrict__ Y,
                                               const float* __restrict__ Ct,
                                               float* __restrict__ A,
                                               float* __restrict__ R) {
    __shared__ float Zt[32 * 128];
    __shared__ float Yt[32 * 128];
    const int t0  = blockIdx.x * 32;
    const int tid = threadIdx.x;
    {
        const float4* Zg = (const float4*)(Z + t0 * S_NO);
        const float4* Yg = (const float4*)(Y + t0 * S_NO);
        float4* Zl = (float4*)Zt;
        float4* Yl = (float4*)Yt;
        for (int q = tid; q < 1024; q += 256) { Zl[q] = Zg[q]; Yl[q] = Yg[q]; }
    }
    __syncthreads();
    const int sg = tid & 31;          // s0 = sg*4
    const int tg = tid >> 5;          // 0..7 -> local t = tg*4 + i
    const int s0 = sg * 4;
    float4 accA[4] = {{0,0,0,0},{0,0,0,0},{0,0,0,0},{0,0,0,0}};
    float4 accR[4] = {{0,0,0,0},{0,0,0,0},{0,0,0,0},{0,0,0,0}};
    for (int k4 = 0; k4 < 32; ++k4) {
        const float4 c0 = *(const float4*)&Ct[(k4 * 4 + 0) * S_NO + s0];
        const float4 c1 = *(const float4*)&Ct[(k4 * 4 + 1) * S_NO + s0];
        const float4 c2 = *(const float4*)&Ct[(k4 * 4 + 2) * S_NO + s0];
        const float4 c3 = *(const float4*)&Ct[(k4 * 4 + 3) * S_NO + s0];
#pragma unroll
        for (int i = 0; i < 4; ++i) {
            const float4 z = *(const float4*)&Zt[(tg * 4 + i) * S_NO + k4 * 4];
            fma4(accA[i], z.x, c0); fma4(accA[i], z.y, c1);
            fma4(accA[i], z.z, c2); fma4(accA[i], z.w, c3);
            const float4 y = *(const float4*)&Yt[(tg * 4 + i) * S_NO + k4 * 4];
            fma4(accR[i], y.x, c0); fma4(accR[i], y.y, c1);
            fma4(accR[i], y.z, c2); fma4(accR[i], y.w, c3);
        }
    }
#pragma unroll
    for (int i = 0; i < 4; ++i) {
        *(float4*)&A[(t0 + tg * 4 + i) * S_NO + s0] = accA[i];
        *(float4*)&R[(t0 + tg * 4 + i) * S_NO + s0] = accR[i];
    }
}

// ---------------------------------------------------------------------------
// K3: fused 100-tap causal conv + final map. NO LDS, no barrier.
// Thread: one s, 16 t's. Conv in 7 chunks of 16 taps with a 31-deep register
// window (all indices static). Taps zero-padded to 112 rows.
// ---------------------------------------------------------------------------
template <bool GUARD>
__device__ __forceinline__ void conv16(const float* __restrict__ A,
                                       const float* __restrict__ kT,
                                       int t0, int s, float acc[16]) {
    for (int c = 0; c < 7; ++c) {
        const int B = t0 - 16 * c - 16;     // window base row
        float w[31];
        float kj[16];
#pragma unroll
        for (int q = 0; q < 31; ++q) {
            const int u = B + q;
            if (GUARD)
                w[q] = (u >= 0) ? A[u * S_NO + s] : 0.0f;
            else
                w[q] = A[u * S_NO + s];
        }
#pragma unroll
        for (int r = 0; r < 16; ++r) kj[r] = kT[(16 * c + r) * S_NO + s];
#pragma unroll
        for (int r = 0; r < 16; ++r)
#pragma unroll
            for (int i = 0; i < 16; ++i)
                acc[i] = fmaf(kj[r], w[i + 15 - r], acc[i]);   // row = B + i+15-r = t0+i-1-j
    }
}

__global__ void __launch_bounds__(256) k3_fused(const float* __restrict__ A,
                                                const float* __restrict__ anc_kT,
                                                const float* __restrict__ S_conv,
                                                const float* __restrict__ noise,
                                                const float* __restrict__ W_sub,
                                                const float* __restrict__ theta_syn,
                                                const float* __restrict__ theta_spike,
                                                const float* __restrict__ W_spike,
                                                const int* __restrict__ flag,
                                                float* __restrict__ out0,
                                                float* __restrict__ out1,
                                                float* __restrict__ out2,
                                                float* __restrict__ out3,
                                                float* __restrict__ Fws) {
    const int tid = threadIdx.x;
    const int s   = tid & 127;
    const int tg  = tid >> 7;                       // wave-uniform
    const int t0  = blockIdx.x * 32 + tg * 16;
    float acc[16] = {0,0,0,0,0,0,0,0,0,0,0,0,0,0,0,0};
    if (t0 >= J_PAD) conv16<false>(A, anc_kT, t0, s, acc);
    else             conv16<true >(A, anc_kT, t0, s, acc);

    if (*flag == 0) {
        const float tsy = theta_syn[s], wsub = W_sub[s];
        const float wsp = W_spike[s],  tsp  = theta_spike[s];
#pragma unroll
        for (int i = 0; i < 16; ++i) {
            const int n = (t0 + i) * S_NO + s;
            const float x  = sigm(S_conv[n] + tsy + out1[n] + acc[i]);
            const float dn = fmaf(x, wsp, tsp);
            const float z  = sigm(dn + noise[n]);
            out0[n] = x * wsub;
            out1[n] = z;
            out2[n] = dn;
            out3[n] = dn;
        }
    } else {
#pragma unroll
        for (int i = 0; i < 16; ++i) Fws[(t0 + i) * S_NO + s] = acc[i];
    }
}

// ---------------------------------------------------------------------------
// K4: exact sequential recurrence (only when hist kernel != 0).
// ---------------------------------------------------------------------------
__global__ void __launch_bounds__(64) k4_scan(const float* __restrict__ S_conv,
                                              const float* __restrict__ noise,
                                              const float* __restrict__ W_sub,
                                              const float* __restrict__ theta_syn,
                                              const float* __restrict__ theta_spike,
                                              const float* __restrict__ W_spike,
                                              const float* __restrict__ hist_k,
                                              const int* __restrict__ flag,
                                              const float* __restrict__ Fws,
                                              float* __restrict__ out0,
                                              float* __restrict__ out1,
                                              float* __restrict__ out2,
                                              float* __restrict__ out3) {
    if (*flag == 0) return;
    __shared__ float zr[128];
    const int s = blockIdx.x;
    const int l = threadIdx.x;
    zr[l] = 0.0f; zr[l + 64] = 0.0f;      // single wave: no barrier needed
    const float hk0 = (l < T_HIST) ? hist_k[s * T_HIST + l] : 0.0f;
    const float hk1 = (l + 64 < T_HIST) ? hist_k[s * T_HIST + l + 64] : 0.0f;
    const float tsy = theta_syn[s], wsub = W_sub[s];
    const float wsp = W_spike[s],  tsp  = theta_spike[s];
    for (int t = 0; t < T_DATA; ++t) {
        float fh = hk0 * zr[(t - 1 - l) & 127];
        fh = fmaf(hk1, zr[(t - 65 - l) & 127], fh);
#pragma unroll
        for (int m = 1; m < 64; m <<= 1) fh += __shfl_xor(fh, m, 64);
        const int n = t * S_NO + s;
        const float basev = S_conv[n] + tsy + out1[n] + Fws[n];
        const float x  = sigm(basev + fh);
        const float dn = fmaf(x, wsp, tsp);
        const float z  = sigm(dn + noise[n]);
        if (l == 0) {
            out0[n] = x * wsub;
            out1[n] = z;
            out2[n] = dn;
            out3[n] = dn;
            zr[t & 127] = z;
        }
    }
}

// ---------------------------------------------------------------------------
extern "C" void kernel_launch(void* const* d_in, const int* in_sizes, int n_in,
                              void* d_out, int out_size, void* d_ws, size_t ws_size,
                              hipStream_t stream) {
    const float* S_conv  = (const float*)d_in[0];
    const float* Y_anc   = (const float*)d_in[1];
    const float* Z_anc   = (const float*)d_in[2];
    const float* noise   = (const float*)d_in[3];
    const float* C_den   = (const float*)d_in[4];
    const float* W_sub   = (const float*)d_in[5];
    const float* th_syn  = (const float*)d_in[6];
    const float* K_spk   = (const float*)d_in[7];
    const float* tau_spk = (const float*)d_in[8];
    const float* dl_spk  = (const float*)d_in[9];
    const float* th_spk  = (const float*)d_in[10];
    const float* W_spk   = (const float*)d_in[11];
    const float* tau_h   = (const float*)d_in[12];
    const float* K_h     = (const float*)d_in[13];
    const float* dl_h    = (const float*)d_in[14];

    float* out  = (float*)d_out;
    float* out0 = out;
    float* out1 = out + NELEM;
    float* out2 = out + 2 * NELEM;
    float* out3 = out + 3 * NELEM;

    // workspace: A | F | Ct | anc_kT (112 rows) | hist_k | flag
    float* ws     = (float*)d_ws;
    float* wsA    = ws;
    float* wsF    = ws + NELEM;
    float* Ct     = ws + 2 * NELEM;
    float* anc_kT = Ct + S_NO * S_NO;
    float* hist_k = anc_kT + J_PAD * S_NO;
    int*   flag   = (int*)(hist_k + S_NO * T_HIST);

    k1_prep<<<17, 256, 0, stream>>>(C_den, K_spk, tau_spk, dl_spk, tau_h, K_h, dl_h,
                                    Ct, anc_kT, hist_k, flag);
    // A -> ws, R -> out1
    k2_gemm<<<T_DATA / 32, 256, 0, stream>>>(Z_anc, Y_anc, Ct, wsA, out1);
    // fused conv + final map (reads A from ws, R from out1)
    k3_fused<<<T_DATA / 32, 256, 0, stream>>>(wsA, anc_kT, S_conv, noise,
                                              W_sub, th_syn, th_spk, W_spk,
                                              flag, out0, out1, out2, out3, wsF);
    // exact sequential path (no-op when hist kernel is all-zero)
    k4_scan<<<S_NO, 64, 0, stream>>>(S_conv, noise, W_sub, th_syn, th_spk, W_spk,
                                     hist_k, flag, wsF, out0, out1, out2, out3);
}